// Round 2
// baseline (1493.843 us; speedup 1.0000x reference)
//
#include <hip/hip_runtime.h>
#include <hip/hip_bf16.h>
#include <math.h>

// Problem constants (match reference)
#define CUTOFF_F 10.0f
#define PI_OVER_CUTOFF 0.31415926535897931f  // pi/10

// ---------------------------------------------------------------------------
// Kernel 1: per-edge aggregation of cutoff-weighted RAW edge features into
// per-node bins. Algebraic factorization (scatter index == gather index, and
// all projections are linear) means we never touch node features here and
// only need 16 floats per node:
//   aggr[n*16 + 0..5]  = sum_e coeff_e * edge_sca[e, 0..5]
//   aggr[n*16 + 6]     = sum_e coeff_e
//   aggr[n*16 + 7..15] = sum_e coeff_e * edge_vec[e, 0..8]
// ---------------------------------------------------------------------------
__global__ __launch_bounds__(256) void edge_aggregate(
    const float* __restrict__ edge_sca,
    const float* __restrict__ edge_vec,
    const float* __restrict__ gds,
    const int* __restrict__ eidx,   // edge_index, row 0 = src
    float* __restrict__ aggr,
    int E)
{
    int e = blockIdx.x * blockDim.x + threadIdx.x;
    if (e >= E) return;

    int src = eidx[e];
    float d = gds[e];
    float coeff = 0.0f;
    if (d >= 0.0f && d <= CUTOFF_F)
        coeff = 0.5f * (__cosf(d * PI_OVER_CUTOFF) + 1.0f);

    float* base = aggr + (size_t)src * 16;
    const float* es = edge_sca + (size_t)e * 6;
    const float* ev = edge_vec + (size_t)e * 9;

#pragma unroll
    for (int c = 0; c < 6; ++c)
        atomicAdd(base + c, coeff * es[c]);
    atomicAdd(base + 6, coeff);
#pragma unroll
    for (int k = 0; k < 9; ++k)
        atomicAdd(base + 7 + k, coeff * ev[k]);
}

// ---------------------------------------------------------------------------
// Kernel 2: per-node everything else. 16 lanes per node (block=256 -> 16
// nodes/block). Weights staged to LDS once per block; per-node intermediates
// in LDS with odd strides to avoid bank conflicts across the 4 nodes of a
// wave (same-address reads across a node's 16 lanes broadcast for free).
// ---------------------------------------------------------------------------
__global__ __launch_bounds__(256) void node_kernel(
    const float* __restrict__ node_sca,
    const float* __restrict__ node_vec,
    const float* __restrict__ aggr,
    const float* __restrict__ W_nss, const float* __restrict__ b_nss,
    const float* __restrict__ W_ess, const float* __restrict__ b_ess,
    const float* __restrict__ W_nsv, const float* __restrict__ b_nsv,
    const float* __restrict__ W_esv, const float* __restrict__ b_esv,
    const float* __restrict__ W_nvv, const float* __restrict__ W_evv,
    const float* __restrict__ W_lv,  const float* __restrict__ W_lv2,
    const float* __restrict__ W_ls,
    const float* __restrict__ W_gate, const float* __restrict__ b_gate,
    const float* __restrict__ W_dir,
    float* __restrict__ out,
    int N)
{
    // ---- weights in LDS ----
    __shared__ float sW_nss[64],  sb_nss[16];
    __shared__ float sW_ess[96],  sb_ess[16];
    __shared__ float sW_nsv[64],  sb_nsv[16];
    __shared__ float sW_esv[96],  sb_esv[16];
    __shared__ float sW_nvv[48],  sW_evv[48];
    __shared__ float sW_lv[256],  sW_lv2[256];
    __shared__ float sW_ls[512];
    __shared__ float sW_gate[256], sb_gate[16];
    __shared__ float sW_dir[256];

    // ---- per-node scratch (odd node-strides -> no bank conflicts) ----
    __shared__ float s_in  [16 * 33];  // [0..3] nsca  [4..12] nvec  [13..18] A  [19] c  [20..28] B
    __shared__ float s_avec[16 * 49];  // aggr_vec  [ch*3+i]
    __shared__ float s_cat [16 * 33];  // [0..15] v_norm, [16..31] aggr_sca
    __shared__ float s_vint[16 * 49];  // v_inter
    __shared__ float s_osca[16 * 17];  // out_sca (pre-activation)
    __shared__ float s_ovec[16 * 49];  // gated out_vec

    const int t = threadIdx.x;
    {
        // cooperative weight load
        for (int i = t; i < 64;  i += 256) { sW_nss[i] = W_nss[i]; sW_nsv[i] = W_nsv[i]; }
        for (int i = t; i < 96;  i += 256) { sW_ess[i] = W_ess[i]; sW_esv[i] = W_esv[i]; }
        for (int i = t; i < 48;  i += 256) { sW_nvv[i] = W_nvv[i]; sW_evv[i] = W_evv[i]; }
        for (int i = t; i < 256; i += 256) {
            sW_lv[i]   = W_lv[i];
            sW_lv2[i]  = W_lv2[i];
            sW_gate[i] = W_gate[i];
            sW_dir[i]  = W_dir[i];
        }
        for (int i = t; i < 512; i += 256) sW_ls[i] = W_ls[i];
        if (t < 16) {
            sb_nss[t]  = b_nss[t];
            sb_ess[t]  = b_ess[t];
            sb_nsv[t]  = b_nsv[t];
            sb_esv[t]  = b_esv[t];
            sb_gate[t] = b_gate[t];
        }
    }

    const int slot = t >> 4;   // node slot within block, 0..15
    const int o    = t & 15;   // output channel, 0..15
    const int n    = blockIdx.x * 16 + slot;
    const bool valid = (n < N);

    // stage per-node inputs (one value per lane)
    if (valid) {
        if (o < 4) s_in[slot * 33 + o]     = node_sca[(size_t)n * 4 + o];
        if (o < 9) s_in[slot * 33 + 4 + o] = node_vec[(size_t)n * 9 + o];
        s_in[slot * 33 + 13 + o] = aggr[(size_t)n * 16 + o];
    }
    __syncthreads();

    const float* in = s_in + slot * 33;

    // node scalar projections
    float nss = sb_nss[o], nsv = sb_nsv[o];
#pragma unroll
    for (int c = 0; c < 4; ++c) {
        float x = in[c];
        nss += x * sW_nss[c * 16 + o];
        nsv += x * sW_nsv[c * 16 + o];
    }
    // node vector projection
    float nvv0 = 0.f, nvv1 = 0.f, nvv2 = 0.f;
#pragma unroll
    for (int c = 0; c < 3; ++c) {
        float w = sW_nvv[c * 16 + o];
        nvv0 += in[4 + c * 3 + 0] * w;
        nvv1 += in[4 + c * 3 + 1] * w;
        nvv2 += in[4 + c * 3 + 2] * w;
    }
    // aggregated edge projections (from factorized sums)
    float cc = in[19];
    float es = cc * sb_ess[o], ev = cc * sb_esv[o];
#pragma unroll
    for (int c = 0; c < 6; ++c) {
        float a = in[13 + c];
        es += a * sW_ess[c * 16 + o];
        ev += a * sW_esv[c * 16 + o];
    }
    float EV0 = 0.f, EV1 = 0.f, EV2 = 0.f;
#pragma unroll
    for (int c = 0; c < 3; ++c) {
        float w = sW_evv[c * 16 + o];
        EV0 += in[20 + c * 3 + 0] * w;
        EV1 += in[20 + c * 3 + 1] * w;
        EV2 += in[20 + c * 3 + 2] * w;
    }

    float asca = nss * es;
    float av0 = nvv0 * ev + nsv * EV0;
    float av1 = nvv1 * ev + nsv * EV1;
    float av2 = nvv2 * ev + nsv * EV2;
    s_avec[slot * 49 + o * 3 + 0] = av0;
    s_avec[slot * 49 + o * 3 + 1] = av1;
    s_avec[slot * 49 + o * 3 + 2] = av2;
    s_cat[slot * 33 + 16 + o] = asca;
    __syncthreads();

    // v_inter = aggr_vec . W_lv
    float vi0 = 0.f, vi1 = 0.f, vi2 = 0.f;
#pragma unroll
    for (int c = 0; c < 16; ++c) {
        float w = sW_lv[c * 16 + o];
        const float* a = &s_avec[slot * 49 + c * 3];
        vi0 += a[0] * w; vi1 += a[1] * w; vi2 += a[2] * w;
    }
    float vnorm = sqrtf(vi0 * vi0 + vi1 * vi1 + vi2 * vi2);
    s_vint[slot * 49 + o * 3 + 0] = vi0;
    s_vint[slot * 49 + o * 3 + 1] = vi1;
    s_vint[slot * 49 + o * 3 + 2] = vi2;
    s_cat[slot * 33 + o] = vnorm;
    __syncthreads();

    // out_sca = [v_norm, aggr_sca] @ W_ls ; out_vec = v_inter . W_lv2
    float osca = 0.f;
#pragma unroll
    for (int c = 0; c < 32; ++c)
        osca += s_cat[slot * 33 + c] * sW_ls[c * 16 + o];
    float ov0 = 0.f, ov1 = 0.f, ov2 = 0.f;
#pragma unroll
    for (int c = 0; c < 16; ++c) {
        float w = sW_lv2[c * 16 + o];
        const float* a = &s_vint[slot * 49 + c * 3];
        ov0 += a[0] * w; ov1 += a[1] * w; ov2 += a[2] * w;
    }
    s_osca[slot * 17 + o] = osca;
    __syncthreads();

    // gate
    float g = sb_gate[o];
#pragma unroll
    for (int c = 0; c < 16; ++c)
        g += s_osca[slot * 17 + c] * sW_gate[c * 16 + o];
    g = 1.0f / (1.0f + __expf(-g));
    ov0 *= g; ov1 *= g; ov2 *= g;
    s_ovec[slot * 49 + o * 3 + 0] = ov0;
    s_ovec[slot * 49 + o * 3 + 1] = ov1;
    s_ovec[slot * 49 + o * 3 + 2] = ov2;
    __syncthreads();

    // VNLeakyReLU
    float dv0 = 0.f, dv1 = 0.f, dv2 = 0.f;
#pragma unroll
    for (int c = 0; c < 16; ++c) {
        float w = sW_dir[c * 16 + o];
        const float* a = &s_ovec[slot * 49 + c * 3];
        dv0 += a[0] * w; dv1 += a[1] * w; dv2 += a[2] * w;
    }
    float dot = ov0 * dv0 + ov1 * dv1 + ov2 * dv2;
    if (dot < 0.0f) {
        float dn = dv0 * dv0 + dv1 * dv1 + dv2 * dv2;
        float f = 0.8f * dot / (dn + 1e-6f);
        ov0 -= f * dv0; ov1 -= f * dv1; ov2 -= f * dv2;
    }

    if (valid) {
        float so = (osca >= 0.0f) ? osca : 0.01f * osca;
        out[(size_t)n * 16 + o] = so;
        size_t vb = (size_t)N * 16 + (size_t)n * 48 + (size_t)o * 3;
        out[vb + 0] = ov0;
        out[vb + 1] = ov1;
        out[vb + 2] = ov2;
    }
}

extern "C" void kernel_launch(void* const* d_in, const int* in_sizes, int n_in,
                              void* d_out, int out_size, void* d_ws, size_t ws_size,
                              hipStream_t stream)
{
    const float* node_sca = (const float*)d_in[0];
    const float* node_vec = (const float*)d_in[1];
    const float* edge_sca = (const float*)d_in[2];
    const float* edge_vec = (const float*)d_in[3];
    const float* gds      = (const float*)d_in[4];
    const int*   eidx     = (const int*)d_in[5];

    const int N = in_sizes[0] / 4;   // node_sca is [N,4]
    const int E = in_sizes[4];       // gds_dist is [E]

    float* aggr = (float*)d_ws;      // N*16 floats
    hipMemsetAsync(aggr, 0, (size_t)N * 16 * sizeof(float), stream);

    edge_aggregate<<<(E + 255) / 256, 256, 0, stream>>>(
        edge_sca, edge_vec, gds, eidx, aggr, E);

    node_kernel<<<(N + 15) / 16, 256, 0, stream>>>(
        node_sca, node_vec, aggr,
        (const float*)d_in[6],  (const float*)d_in[7],
        (const float*)d_in[8],  (const float*)d_in[9],
        (const float*)d_in[10], (const float*)d_in[11],
        (const float*)d_in[12], (const float*)d_in[13],
        (const float*)d_in[14], (const float*)d_in[15],
        (const float*)d_in[16], (const float*)d_in[17],
        (const float*)d_in[18],
        (const float*)d_in[19], (const float*)d_in[20],
        (const float*)d_in[21],
        (float*)d_out, N);
}

// Round 3
// 413.060 us; speedup vs baseline: 3.6165x; 3.6165x over previous
//
#include <hip/hip_runtime.h>
#include <math.h>

// Problem constants (match reference)
#define CUTOFF_F 10.0f
#define PI_OVER_CUTOFF 0.31415926535897931f  // pi/10
#define KCAP 64   // per-node bucket capacity; P(deg>64) ~ 1e-14 at Poisson(16)

// ---------------------------------------------------------------------------
// Fast path kernel 1: counting-sort-lite. One int atomic per edge (ticket),
// then a plain write of the edge id. Replaces 16 fp atomics/edge with 1 int
// atomic + 1 scattered 4B store.
// ---------------------------------------------------------------------------
__global__ __launch_bounds__(256) void fill_buckets(
    const int* __restrict__ eidx,
    int* __restrict__ count,
    int* __restrict__ bucket,
    int E)
{
    int e = blockIdx.x * blockDim.x + threadIdx.x;
    if (e >= E) return;
    int src = eidx[e];
    int slot = atomicAdd(&count[src], 1);
    if (slot < KCAP) bucket[src * KCAP + slot] = e;
}

// ---------------------------------------------------------------------------
// Fallback kernel (round-2 path): per-edge fp atomics into aggr[n*16..].
// Used only if ws_size is too small for the bucket path.
// ---------------------------------------------------------------------------
__global__ __launch_bounds__(256) void edge_aggregate(
    const float* __restrict__ edge_sca,
    const float* __restrict__ edge_vec,
    const float* __restrict__ gds,
    const int* __restrict__ eidx,
    float* __restrict__ aggr,
    int E)
{
    int e = blockIdx.x * blockDim.x + threadIdx.x;
    if (e >= E) return;
    int src = eidx[e];
    float d = gds[e];
    float coeff = 0.0f;
    if (d >= 0.0f && d <= CUTOFF_F)
        coeff = 0.5f * (__cosf(d * PI_OVER_CUTOFF) + 1.0f);
    float* base = aggr + (size_t)src * 16;
    const float* es = edge_sca + (size_t)e * 6;
    const float* ev = edge_vec + (size_t)e * 9;
#pragma unroll
    for (int c = 0; c < 6; ++c) atomicAdd(base + c, coeff * es[c]);
    atomicAdd(base + 6, coeff);
#pragma unroll
    for (int k = 0; k < 9; ++k) atomicAdd(base + 7 + k, coeff * ev[k]);
}

// ---------------------------------------------------------------------------
// Fused kernel: per-node gather (atomic-free, register accumulation) + all
// projections + GVLinear + gate + VNLeakyReLU. 16 lanes per node, 16 nodes
// per 256-block. Weights staged in LDS once per block.
// use_buckets: 1 -> gather from bucket/count; 0 -> read precomputed aggr.
// ---------------------------------------------------------------------------
__global__ __launch_bounds__(256) void node_fused(
    const float* __restrict__ node_sca,
    const float* __restrict__ node_vec,
    const float* __restrict__ edge_sca,
    const float* __restrict__ edge_vec,
    const float* __restrict__ gds,
    const int* __restrict__ count,
    const int* __restrict__ bucket,
    const float* __restrict__ aggr,
    const float* __restrict__ W_nss, const float* __restrict__ b_nss,
    const float* __restrict__ W_ess, const float* __restrict__ b_ess,
    const float* __restrict__ W_nsv, const float* __restrict__ b_nsv,
    const float* __restrict__ W_esv, const float* __restrict__ b_esv,
    const float* __restrict__ W_nvv, const float* __restrict__ W_evv,
    const float* __restrict__ W_lv,  const float* __restrict__ W_lv2,
    const float* __restrict__ W_ls,
    const float* __restrict__ W_gate, const float* __restrict__ b_gate,
    const float* __restrict__ W_dir,
    float* __restrict__ out,
    int N, int use_buckets)
{
    // ---- weights in LDS ----
    __shared__ float sW_nss[64],  sb_nss[16];
    __shared__ float sW_ess[96],  sb_ess[16];
    __shared__ float sW_nsv[64],  sb_nsv[16];
    __shared__ float sW_esv[96],  sb_esv[16];
    __shared__ float sW_nvv[48],  sW_evv[48];
    __shared__ float sW_lv[256],  sW_lv2[256];
    __shared__ float sW_ls[512];
    __shared__ float sW_gate[256], sb_gate[16];
    __shared__ float sW_dir[256];

    // ---- per-node scratch (odd node-strides -> no bank conflicts) ----
    __shared__ float s_in  [16 * 33];
    __shared__ float s_avec[16 * 49];
    __shared__ float s_cat [16 * 33];
    __shared__ float s_vint[16 * 49];
    __shared__ float s_osca[16 * 17];
    __shared__ float s_ovec[16 * 49];

    const int t = threadIdx.x;
    {
        for (int i = t; i < 64;  i += 256) { sW_nss[i] = W_nss[i]; sW_nsv[i] = W_nsv[i]; }
        for (int i = t; i < 96;  i += 256) { sW_ess[i] = W_ess[i]; sW_esv[i] = W_esv[i]; }
        for (int i = t; i < 48;  i += 256) { sW_nvv[i] = W_nvv[i]; sW_evv[i] = W_evv[i]; }
        for (int i = t; i < 256; i += 256) {
            sW_lv[i]   = W_lv[i];
            sW_lv2[i]  = W_lv2[i];
            sW_gate[i] = W_gate[i];
            sW_dir[i]  = W_dir[i];
        }
        for (int i = t; i < 512; i += 256) sW_ls[i] = W_ls[i];
        if (t < 16) {
            sb_nss[t]  = b_nss[t];
            sb_ess[t]  = b_ess[t];
            sb_nsv[t]  = b_nsv[t];
            sb_esv[t]  = b_esv[t];
            sb_gate[t] = b_gate[t];
        }
    }

    const int slot = t >> 4;   // node slot within block
    const int o    = t & 15;   // channel
    const int n    = blockIdx.x * 16 + slot;
    const bool valid = (n < N);

    // ---- stage per-node inputs + aggregate edge sums ----
    if (valid) {
        if (o < 4) s_in[slot * 33 + o]     = node_sca[(size_t)n * 4 + o];
        if (o < 9) s_in[slot * 33 + 4 + o] = node_vec[(size_t)n * 9 + o];
    }

    if (use_buckets) {
        float acc = 0.0f;
        int cnt = valid ? count[n] : 0;       // broadcast within 16-lane group
        if (cnt > KCAP) cnt = KCAP;
        const int* bk = bucket + (size_t)n * KCAP;
        for (int s = 0; s < cnt; ++s) {
            int e = bk[s];                    // broadcast load
            float d = gds[e];                 // broadcast load
            float coeff = 0.0f;
            if (d >= 0.0f && d <= CUTOFF_F)
                coeff = 0.5f * (__cosf(d * PI_OVER_CUTOFF) + 1.0f);
            float feat;
            if (o < 6)       feat = edge_sca[(size_t)e * 6 + o];
            else if (o == 6) feat = 1.0f;
            else             feat = edge_vec[(size_t)e * 9 + (o - 7)];
            acc += coeff * feat;
        }
        if (valid) s_in[slot * 33 + 13 + o] = acc;
    } else {
        if (valid) s_in[slot * 33 + 13 + o] = aggr[(size_t)n * 16 + o];
    }
    __syncthreads();

    const float* in = s_in + slot * 33;

    // node scalar projections
    float nss = sb_nss[o], nsv = sb_nsv[o];
#pragma unroll
    for (int c = 0; c < 4; ++c) {
        float x = in[c];
        nss += x * sW_nss[c * 16 + o];
        nsv += x * sW_nsv[c * 16 + o];
    }
    // node vector projection
    float nvv0 = 0.f, nvv1 = 0.f, nvv2 = 0.f;
#pragma unroll
    for (int c = 0; c < 3; ++c) {
        float w = sW_nvv[c * 16 + o];
        nvv0 += in[4 + c * 3 + 0] * w;
        nvv1 += in[4 + c * 3 + 1] * w;
        nvv2 += in[4 + c * 3 + 2] * w;
    }
    // aggregated edge projections (factorized sums)
    float cc = in[19];
    float es = cc * sb_ess[o], ev = cc * sb_esv[o];
#pragma unroll
    for (int c = 0; c < 6; ++c) {
        float a = in[13 + c];
        es += a * sW_ess[c * 16 + o];
        ev += a * sW_esv[c * 16 + o];
    }
    float EV0 = 0.f, EV1 = 0.f, EV2 = 0.f;
#pragma unroll
    for (int c = 0; c < 3; ++c) {
        float w = sW_evv[c * 16 + o];
        EV0 += in[20 + c * 3 + 0] * w;
        EV1 += in[20 + c * 3 + 1] * w;
        EV2 += in[20 + c * 3 + 2] * w;
    }

    float asca = nss * es;
    float av0 = nvv0 * ev + nsv * EV0;
    float av1 = nvv1 * ev + nsv * EV1;
    float av2 = nvv2 * ev + nsv * EV2;
    s_avec[slot * 49 + o * 3 + 0] = av0;
    s_avec[slot * 49 + o * 3 + 1] = av1;
    s_avec[slot * 49 + o * 3 + 2] = av2;
    s_cat[slot * 33 + 16 + o] = asca;
    __syncthreads();

    // v_inter = aggr_vec . W_lv
    float vi0 = 0.f, vi1 = 0.f, vi2 = 0.f;
#pragma unroll
    for (int c = 0; c < 16; ++c) {
        float w = sW_lv[c * 16 + o];
        const float* a = &s_avec[slot * 49 + c * 3];
        vi0 += a[0] * w; vi1 += a[1] * w; vi2 += a[2] * w;
    }
    float vnorm = sqrtf(vi0 * vi0 + vi1 * vi1 + vi2 * vi2);
    s_vint[slot * 49 + o * 3 + 0] = vi0;
    s_vint[slot * 49 + o * 3 + 1] = vi1;
    s_vint[slot * 49 + o * 3 + 2] = vi2;
    s_cat[slot * 33 + o] = vnorm;
    __syncthreads();

    // out_sca = [v_norm, aggr_sca] @ W_ls ; out_vec = v_inter . W_lv2
    float osca = 0.f;
#pragma unroll
    for (int c = 0; c < 32; ++c)
        osca += s_cat[slot * 33 + c] * sW_ls[c * 16 + o];
    float ov0 = 0.f, ov1 = 0.f, ov2 = 0.f;
#pragma unroll
    for (int c = 0; c < 16; ++c) {
        float w = sW_lv2[c * 16 + o];
        const float* a = &s_vint[slot * 49 + c * 3];
        ov0 += a[0] * w; ov1 += a[1] * w; ov2 += a[2] * w;
    }
    s_osca[slot * 17 + o] = osca;
    __syncthreads();

    // gate
    float g = sb_gate[o];
#pragma unroll
    for (int c = 0; c < 16; ++c)
        g += s_osca[slot * 17 + c] * sW_gate[c * 16 + o];
    g = 1.0f / (1.0f + __expf(-g));
    ov0 *= g; ov1 *= g; ov2 *= g;
    s_ovec[slot * 49 + o * 3 + 0] = ov0;
    s_ovec[slot * 49 + o * 3 + 1] = ov1;
    s_ovec[slot * 49 + o * 3 + 2] = ov2;
    __syncthreads();

    // VNLeakyReLU
    float dv0 = 0.f, dv1 = 0.f, dv2 = 0.f;
#pragma unroll
    for (int c = 0; c < 16; ++c) {
        float w = sW_dir[c * 16 + o];
        const float* a = &s_ovec[slot * 49 + c * 3];
        dv0 += a[0] * w; dv1 += a[1] * w; dv2 += a[2] * w;
    }
    float dot = ov0 * dv0 + ov1 * dv1 + ov2 * dv2;
    if (dot < 0.0f) {
        float dn = dv0 * dv0 + dv1 * dv1 + dv2 * dv2;
        float f = 0.8f * dot / (dn + 1e-6f);
        ov0 -= f * dv0; ov1 -= f * dv1; ov2 -= f * dv2;
    }

    if (valid) {
        float so = (osca >= 0.0f) ? osca : 0.01f * osca;
        out[(size_t)n * 16 + o] = so;
        size_t vb = (size_t)N * 16 + (size_t)n * 48 + (size_t)o * 3;
        out[vb + 0] = ov0;
        out[vb + 1] = ov1;
        out[vb + 2] = ov2;
    }
}

extern "C" void kernel_launch(void* const* d_in, const int* in_sizes, int n_in,
                              void* d_out, int out_size, void* d_ws, size_t ws_size,
                              hipStream_t stream)
{
    const float* node_sca = (const float*)d_in[0];
    const float* node_vec = (const float*)d_in[1];
    const float* edge_sca = (const float*)d_in[2];
    const float* edge_vec = (const float*)d_in[3];
    const float* gds      = (const float*)d_in[4];
    const int*   eidx     = (const int*)d_in[5];

    const int N = in_sizes[0] / 4;   // node_sca is [N,4]
    const int E = in_sizes[4];       // gds_dist is [E]

    const size_t need = (size_t)N * (1 + KCAP) * sizeof(int);
    const int use_buckets = (ws_size >= need) ? 1 : 0;

    int*   count  = (int*)d_ws;            // N ints
    int*   bucket = count + N;             // N*KCAP ints
    float* aggr   = (float*)d_ws;          // fallback: N*16 floats

    if (use_buckets) {
        hipMemsetAsync(count, 0, (size_t)N * sizeof(int), stream);
        fill_buckets<<<(E + 255) / 256, 256, 0, stream>>>(eidx, count, bucket, E);
    } else {
        hipMemsetAsync(aggr, 0, (size_t)N * 16 * sizeof(float), stream);
        edge_aggregate<<<(E + 255) / 256, 256, 0, stream>>>(
            edge_sca, edge_vec, gds, eidx, aggr, E);
    }

    node_fused<<<(N + 15) / 16, 256, 0, stream>>>(
        node_sca, node_vec, edge_sca, edge_vec, gds,
        count, bucket, aggr,
        (const float*)d_in[6],  (const float*)d_in[7],
        (const float*)d_in[8],  (const float*)d_in[9],
        (const float*)d_in[10], (const float*)d_in[11],
        (const float*)d_in[12], (const float*)d_in[13],
        (const float*)d_in[14], (const float*)d_in[15],
        (const float*)d_in[16], (const float*)d_in[17],
        (const float*)d_in[18],
        (const float*)d_in[19], (const float*)d_in[20],
        (const float*)d_in[21],
        (float*)d_out, N, use_buckets);
}

// Round 4
// 364.118 us; speedup vs baseline: 4.1026x; 1.1344x over previous
//
#include <hip/hip_runtime.h>
#include <math.h>

// Problem constants (match reference)
#define CUTOFF_F 10.0f
#define PI_OVER_CUTOFF 0.31415926535897931f  // pi/10
#define KCAP 64   // fallback bucket capacity

// ===========================================================================
// CSR fast path
// ===========================================================================

// Kernel 1: count edges per node; remember each edge's slot within its node.
__global__ __launch_bounds__(256) void count_edges(
    const int* __restrict__ eidx,
    int* __restrict__ count,
    int* __restrict__ slotOf,
    int E)
{
    int e = blockIdx.x * blockDim.x + threadIdx.x;
    if (e >= E) return;
    int src = eidx[e];
    slotOf[e] = atomicAdd(&count[src], 1);
}

// Scan step 1: per-block sums of count[]
__global__ __launch_bounds__(256) void scan_block_sums(
    const int* __restrict__ count, int* __restrict__ blockSums, int N)
{
    __shared__ int sdata[256];
    int t = threadIdx.x;
    int i = blockIdx.x * 256 + t;
    sdata[t] = (i < N) ? count[i] : 0;
    __syncthreads();
    for (int off = 128; off > 0; off >>= 1) {
        if (t < off) sdata[t] += sdata[t + off];
        __syncthreads();
    }
    if (t == 0) blockSums[blockIdx.x] = sdata[0];
}

// Scan step 2: exclusive scan of the (<=1024) block sums, single block.
__global__ __launch_bounds__(1024) void scan_exclusive_small(
    int* __restrict__ blockSums, int M)
{
    __shared__ int s[1024];
    int t = threadIdx.x;
    int orig = (t < M) ? blockSums[t] : 0;
    s[t] = orig;
    __syncthreads();
    for (int off = 1; off < 1024; off <<= 1) {
        int v = (t >= off) ? s[t - off] : 0;
        __syncthreads();
        s[t] += v;
        __syncthreads();
    }
    if (t < M) blockSums[t] = s[t] - orig;   // exclusive
}

// Scan step 3: block-local exclusive scan + block prefix -> offsets[]
__global__ __launch_bounds__(256) void scan_final(
    const int* __restrict__ count, const int* __restrict__ blockSums,
    int* __restrict__ offsets, int N)
{
    __shared__ int s[256];
    int t = threadIdx.x;
    int i = blockIdx.x * 256 + t;
    int orig = (i < N) ? count[i] : 0;
    s[t] = orig;
    __syncthreads();
    for (int off = 1; off < 256; off <<= 1) {
        int v = (t >= off) ? s[t - off] : 0;
        __syncthreads();
        s[t] += v;
        __syncthreads();
    }
    if (i < N) offsets[i] = s[t] - orig + blockSums[blockIdx.x];
}

// Kernel 2: scatter cutoff-weighted compact features (16 floats, one aligned
// 64B segment per edge) to CSR position. Reads coalesced, writes packed.
__global__ __launch_bounds__(256) void scatter_payload(
    const float* __restrict__ edge_sca,
    const float* __restrict__ edge_vec,
    const float* __restrict__ gds,
    const int* __restrict__ eidx,
    const int* __restrict__ slotOf,
    const int* __restrict__ offsets,
    float* __restrict__ payload,
    int E)
{
    int e = blockIdx.x * blockDim.x + threadIdx.x;
    if (e >= E) return;

    int src = eidx[e];
    float d = gds[e];
    float c = 0.0f;
    if (d >= 0.0f && d <= CUTOFF_F)
        c = 0.5f * (__cosf(d * PI_OVER_CUTOFF) + 1.0f);

    const float* es = edge_sca + (size_t)e * 6;
    const float* ev = edge_vec + (size_t)e * 9;

    float4 p0 = { c * es[0], c * es[1], c * es[2], c * es[3] };
    float4 p1 = { c * es[4], c * es[5], c,         c * ev[0] };
    float4 p2 = { c * ev[1], c * ev[2], c * ev[3], c * ev[4] };
    float4 p3 = { c * ev[5], c * ev[6], c * ev[7], c * ev[8] };

    float4* pb = (float4*)(payload + (size_t)(offsets[src] + slotOf[e]) * 16);
    pb[0] = p0; pb[1] = p1; pb[2] = p2; pb[3] = p3;
}

// ===========================================================================
// Fallback kernels (round-3 bucket path / round-2 atomic path)
// ===========================================================================
__global__ __launch_bounds__(256) void fill_buckets(
    const int* __restrict__ eidx, int* __restrict__ count,
    int* __restrict__ bucket, int E)
{
    int e = blockIdx.x * blockDim.x + threadIdx.x;
    if (e >= E) return;
    int src = eidx[e];
    int slot = atomicAdd(&count[src], 1);
    if (slot < KCAP) bucket[src * KCAP + slot] = e;
}

__global__ __launch_bounds__(256) void edge_aggregate(
    const float* __restrict__ edge_sca, const float* __restrict__ edge_vec,
    const float* __restrict__ gds, const int* __restrict__ eidx,
    float* __restrict__ aggr, int E)
{
    int e = blockIdx.x * blockDim.x + threadIdx.x;
    if (e >= E) return;
    int src = eidx[e];
    float d = gds[e];
    float coeff = 0.0f;
    if (d >= 0.0f && d <= CUTOFF_F)
        coeff = 0.5f * (__cosf(d * PI_OVER_CUTOFF) + 1.0f);
    float* base = aggr + (size_t)src * 16;
    const float* es = edge_sca + (size_t)e * 6;
    const float* ev = edge_vec + (size_t)e * 9;
#pragma unroll
    for (int c = 0; c < 6; ++c) atomicAdd(base + c, coeff * es[c]);
    atomicAdd(base + 6, coeff);
#pragma unroll
    for (int k = 0; k < 9; ++k) atomicAdd(base + 7 + k, coeff * ev[k]);
}

// ===========================================================================
// Fused node kernel. mode: 2 = CSR payload, 1 = bucket gather, 0 = aggr read.
// 16 lanes per node, 16 nodes per 256-block.
// ===========================================================================
__global__ __launch_bounds__(256) void node_fused(
    const float* __restrict__ node_sca,
    const float* __restrict__ node_vec,
    const float* __restrict__ edge_sca,
    const float* __restrict__ edge_vec,
    const float* __restrict__ gds,
    const int* __restrict__ count,
    const int* __restrict__ bucket,     // mode 1
    const int* __restrict__ offsets,    // mode 2
    const float* __restrict__ payload,  // mode 2
    const float* __restrict__ aggr,     // mode 0
    const float* __restrict__ W_nss, const float* __restrict__ b_nss,
    const float* __restrict__ W_ess, const float* __restrict__ b_ess,
    const float* __restrict__ W_nsv, const float* __restrict__ b_nsv,
    const float* __restrict__ W_esv, const float* __restrict__ b_esv,
    const float* __restrict__ W_nvv, const float* __restrict__ W_evv,
    const float* __restrict__ W_lv,  const float* __restrict__ W_lv2,
    const float* __restrict__ W_ls,
    const float* __restrict__ W_gate, const float* __restrict__ b_gate,
    const float* __restrict__ W_dir,
    float* __restrict__ out,
    int N, int mode)
{
    // ---- weights in LDS ----
    __shared__ float sW_nss[64],  sb_nss[16];
    __shared__ float sW_ess[96],  sb_ess[16];
    __shared__ float sW_nsv[64],  sb_nsv[16];
    __shared__ float sW_esv[96],  sb_esv[16];
    __shared__ float sW_nvv[48],  sW_evv[48];
    __shared__ float sW_lv[256],  sW_lv2[256];
    __shared__ float sW_ls[512];
    __shared__ float sW_gate[256], sb_gate[16];
    __shared__ float sW_dir[256];

    // ---- per-node scratch (odd node-strides -> no bank conflicts) ----
    __shared__ float s_in  [16 * 33];
    __shared__ float s_avec[16 * 49];
    __shared__ float s_cat [16 * 33];
    __shared__ float s_vint[16 * 49];
    __shared__ float s_osca[16 * 17];
    __shared__ float s_ovec[16 * 49];

    const int t = threadIdx.x;
    {
        for (int i = t; i < 64;  i += 256) { sW_nss[i] = W_nss[i]; sW_nsv[i] = W_nsv[i]; }
        for (int i = t; i < 96;  i += 256) { sW_ess[i] = W_ess[i]; sW_esv[i] = W_esv[i]; }
        for (int i = t; i < 48;  i += 256) { sW_nvv[i] = W_nvv[i]; sW_evv[i] = W_evv[i]; }
        for (int i = t; i < 256; i += 256) {
            sW_lv[i]   = W_lv[i];
            sW_lv2[i]  = W_lv2[i];
            sW_gate[i] = W_gate[i];
            sW_dir[i]  = W_dir[i];
        }
        for (int i = t; i < 512; i += 256) sW_ls[i] = W_ls[i];
        if (t < 16) {
            sb_nss[t]  = b_nss[t];
            sb_ess[t]  = b_ess[t];
            sb_nsv[t]  = b_nsv[t];
            sb_esv[t]  = b_esv[t];
            sb_gate[t] = b_gate[t];
        }
    }

    const int slot = t >> 4;
    const int o    = t & 15;
    const int n    = blockIdx.x * 16 + slot;
    const bool valid = (n < N);

    if (valid) {
        if (o < 4) s_in[slot * 33 + o]     = node_sca[(size_t)n * 4 + o];
        if (o < 9) s_in[slot * 33 + 4 + o] = node_vec[(size_t)n * 9 + o];
    }

    if (mode == 2) {
        // CSR gather: contiguous, packed 64B per edge-slot.
        float acc0 = 0.0f, acc1 = 0.0f;
        if (valid) {
            int cnt = count[n];
            const float* p = payload + (size_t)offsets[n] * 16 + o;
            int s = 0;
            for (; s + 1 < cnt; s += 2) {
                acc0 += p[(size_t)s * 16];
                acc1 += p[(size_t)(s + 1) * 16];
            }
            if (s < cnt) acc0 += p[(size_t)s * 16];
            s_in[slot * 33 + 13 + o] = acc0 + acc1;
        }
    } else if (mode == 1) {
        float acc = 0.0f;
        int cnt = valid ? count[n] : 0;
        if (cnt > KCAP) cnt = KCAP;
        const int* bk = bucket + (size_t)n * KCAP;
        for (int s = 0; s < cnt; ++s) {
            int e = bk[s];
            float d = gds[e];
            float coeff = 0.0f;
            if (d >= 0.0f && d <= CUTOFF_F)
                coeff = 0.5f * (__cosf(d * PI_OVER_CUTOFF) + 1.0f);
            float feat;
            if (o < 6)       feat = edge_sca[(size_t)e * 6 + o];
            else if (o == 6) feat = 1.0f;
            else             feat = edge_vec[(size_t)e * 9 + (o - 7)];
            acc += coeff * feat;
        }
        if (valid) s_in[slot * 33 + 13 + o] = acc;
    } else {
        if (valid) s_in[slot * 33 + 13 + o] = aggr[(size_t)n * 16 + o];
    }
    __syncthreads();

    const float* in = s_in + slot * 33;

    float nss = sb_nss[o], nsv = sb_nsv[o];
#pragma unroll
    for (int c = 0; c < 4; ++c) {
        float x = in[c];
        nss += x * sW_nss[c * 16 + o];
        nsv += x * sW_nsv[c * 16 + o];
    }
    float nvv0 = 0.f, nvv1 = 0.f, nvv2 = 0.f;
#pragma unroll
    for (int c = 0; c < 3; ++c) {
        float w = sW_nvv[c * 16 + o];
        nvv0 += in[4 + c * 3 + 0] * w;
        nvv1 += in[4 + c * 3 + 1] * w;
        nvv2 += in[4 + c * 3 + 2] * w;
    }
    float cc = in[19];
    float es = cc * sb_ess[o], ev = cc * sb_esv[o];
#pragma unroll
    for (int c = 0; c < 6; ++c) {
        float a = in[13 + c];
        es += a * sW_ess[c * 16 + o];
        ev += a * sW_esv[c * 16 + o];
    }
    float EV0 = 0.f, EV1 = 0.f, EV2 = 0.f;
#pragma unroll
    for (int c = 0; c < 3; ++c) {
        float w = sW_evv[c * 16 + o];
        EV0 += in[20 + c * 3 + 0] * w;
        EV1 += in[20 + c * 3 + 1] * w;
        EV2 += in[20 + c * 3 + 2] * w;
    }

    float asca = nss * es;
    float av0 = nvv0 * ev + nsv * EV0;
    float av1 = nvv1 * ev + nsv * EV1;
    float av2 = nvv2 * ev + nsv * EV2;
    s_avec[slot * 49 + o * 3 + 0] = av0;
    s_avec[slot * 49 + o * 3 + 1] = av1;
    s_avec[slot * 49 + o * 3 + 2] = av2;
    s_cat[slot * 33 + 16 + o] = asca;
    __syncthreads();

    float vi0 = 0.f, vi1 = 0.f, vi2 = 0.f;
#pragma unroll
    for (int c = 0; c < 16; ++c) {
        float w = sW_lv[c * 16 + o];
        const float* a = &s_avec[slot * 49 + c * 3];
        vi0 += a[0] * w; vi1 += a[1] * w; vi2 += a[2] * w;
    }
    float vnorm = sqrtf(vi0 * vi0 + vi1 * vi1 + vi2 * vi2);
    s_vint[slot * 49 + o * 3 + 0] = vi0;
    s_vint[slot * 49 + o * 3 + 1] = vi1;
    s_vint[slot * 49 + o * 3 + 2] = vi2;
    s_cat[slot * 33 + o] = vnorm;
    __syncthreads();

    float osca = 0.f;
#pragma unroll
    for (int c = 0; c < 32; ++c)
        osca += s_cat[slot * 33 + c] * sW_ls[c * 16 + o];
    float ov0 = 0.f, ov1 = 0.f, ov2 = 0.f;
#pragma unroll
    for (int c = 0; c < 16; ++c) {
        float w = sW_lv2[c * 16 + o];
        const float* a = &s_vint[slot * 49 + c * 3];
        ov0 += a[0] * w; ov1 += a[1] * w; ov2 += a[2] * w;
    }
    s_osca[slot * 17 + o] = osca;
    __syncthreads();

    float g = sb_gate[o];
#pragma unroll
    for (int c = 0; c < 16; ++c)
        g += s_osca[slot * 17 + c] * sW_gate[c * 16 + o];
    g = 1.0f / (1.0f + __expf(-g));
    ov0 *= g; ov1 *= g; ov2 *= g;
    s_ovec[slot * 49 + o * 3 + 0] = ov0;
    s_ovec[slot * 49 + o * 3 + 1] = ov1;
    s_ovec[slot * 49 + o * 3 + 2] = ov2;
    __syncthreads();

    float dv0 = 0.f, dv1 = 0.f, dv2 = 0.f;
#pragma unroll
    for (int c = 0; c < 16; ++c) {
        float w = sW_dir[c * 16 + o];
        const float* a = &s_ovec[slot * 49 + c * 3];
        dv0 += a[0] * w; dv1 += a[1] * w; dv2 += a[2] * w;
    }
    float dot = ov0 * dv0 + ov1 * dv1 + ov2 * dv2;
    if (dot < 0.0f) {
        float dn = dv0 * dv0 + dv1 * dv1 + dv2 * dv2;
        float f = 0.8f * dot / (dn + 1e-6f);
        ov0 -= f * dv0; ov1 -= f * dv1; ov2 -= f * dv2;
    }

    if (valid) {
        float so = (osca >= 0.0f) ? osca : 0.01f * osca;
        out[(size_t)n * 16 + o] = so;
        size_t vb = (size_t)N * 16 + (size_t)n * 48 + (size_t)o * 3;
        out[vb + 0] = ov0;
        out[vb + 1] = ov1;
        out[vb + 2] = ov2;
    }
}

extern "C" void kernel_launch(void* const* d_in, const int* in_sizes, int n_in,
                              void* d_out, int out_size, void* d_ws, size_t ws_size,
                              hipStream_t stream)
{
    const float* node_sca = (const float*)d_in[0];
    const float* node_vec = (const float*)d_in[1];
    const float* edge_sca = (const float*)d_in[2];
    const float* edge_vec = (const float*)d_in[3];
    const float* gds      = (const float*)d_in[4];
    const int*   eidx     = (const int*)d_in[5];

    const int N = in_sizes[0] / 4;   // node_sca is [N,4]
    const int E = in_sizes[4];       // gds_dist is [E]

    // ---- workspace layout for CSR path ----
    int*   count     = (int*)d_ws;                 // N
    int*   offsets   = count + N;                  // N
    int*   blockSums = offsets + N;                // 1024
    int*   slotOf    = blockSums + 1024;           // E
    size_t hdr_bytes = ((size_t)(2 * N + 1024 + E) * 4 + 63) & ~(size_t)63;
    float* payload   = (float*)((char*)d_ws + hdr_bytes);
    size_t need_csr  = hdr_bytes + (size_t)E * 16 * 4;
    size_t need_bkt  = (size_t)N * (1 + KCAP) * sizeof(int);

    const int nBlocksN = (N + 255) / 256;   // <= 1024 assumed (N <= 262144)

    int mode;
    if (ws_size >= need_csr && nBlocksN <= 1024) mode = 2;
    else if (ws_size >= need_bkt)                mode = 1;
    else                                         mode = 0;

    int* bucket = count + N;        // mode 1: N*KCAP ints after count
    float* aggr = (float*)d_ws;     // mode 0: N*16 floats

    if (mode == 2) {
        hipMemsetAsync(count, 0, (size_t)N * sizeof(int), stream);
        count_edges<<<(E + 255) / 256, 256, 0, stream>>>(eidx, count, slotOf, E);
        scan_block_sums<<<nBlocksN, 256, 0, stream>>>(count, blockSums, N);
        scan_exclusive_small<<<1, 1024, 0, stream>>>(blockSums, nBlocksN);
        scan_final<<<nBlocksN, 256, 0, stream>>>(count, blockSums, offsets, N);
        scatter_payload<<<(E + 255) / 256, 256, 0, stream>>>(
            edge_sca, edge_vec, gds, eidx, slotOf, offsets, payload, E);
    } else if (mode == 1) {
        hipMemsetAsync(count, 0, (size_t)N * sizeof(int), stream);
        fill_buckets<<<(E + 255) / 256, 256, 0, stream>>>(eidx, count, bucket, E);
    } else {
        hipMemsetAsync(aggr, 0, (size_t)N * 16 * sizeof(float), stream);
        edge_aggregate<<<(E + 255) / 256, 256, 0, stream>>>(
            edge_sca, edge_vec, gds, eidx, aggr, E);
    }

    node_fused<<<(N + 15) / 16, 256, 0, stream>>>(
        node_sca, node_vec, edge_sca, edge_vec, gds,
        count, bucket, offsets, payload, aggr,
        (const float*)d_in[6],  (const float*)d_in[7],
        (const float*)d_in[8],  (const float*)d_in[9],
        (const float*)d_in[10], (const float*)d_in[11],
        (const float*)d_in[12], (const float*)d_in[13],
        (const float*)d_in[14], (const float*)d_in[15],
        (const float*)d_in[16], (const float*)d_in[17],
        (const float*)d_in[18],
        (const float*)d_in[19], (const float*)d_in[20],
        (const float*)d_in[21],
        (float*)d_out, N, mode);
}

// Round 5
// 358.038 us; speedup vs baseline: 4.1723x; 1.0170x over previous
//
#include <hip/hip_runtime.h>
#include <hip/hip_fp16.h>
#include <math.h>

// Problem constants (match reference)
#define CUTOFF_F 10.0f
#define PI_OVER_CUTOFF 0.31415926535897931f  // pi/10
#define KCAP 64   // fallback bucket capacity

// ===========================================================================
// CSR fast path
// ===========================================================================

// Kernel 1: count edges per node; remember each edge's slot within its node.
__global__ __launch_bounds__(256) void count_edges(
    const int* __restrict__ eidx,
    int* __restrict__ count,
    int* __restrict__ slotOf,
    int E)
{
    int e = blockIdx.x * blockDim.x + threadIdx.x;
    if (e >= E) return;
    int src = eidx[e];
    slotOf[e] = atomicAdd(&count[src], 1);
}

// Scan step 1: per-block sums of count[]
__global__ __launch_bounds__(256) void scan_block_sums(
    const int* __restrict__ count, int* __restrict__ blockSums, int N)
{
    __shared__ int sdata[256];
    int t = threadIdx.x;
    int i = blockIdx.x * 256 + t;
    sdata[t] = (i < N) ? count[i] : 0;
    __syncthreads();
    for (int off = 128; off > 0; off >>= 1) {
        if (t < off) sdata[t] += sdata[t + off];
        __syncthreads();
    }
    if (t == 0) blockSums[blockIdx.x] = sdata[0];
}

// Scan step 2: exclusive scan of the (<=1024) block sums, single block.
__global__ __launch_bounds__(1024) void scan_exclusive_small(
    int* __restrict__ blockSums, int M)
{
    __shared__ int s[1024];
    int t = threadIdx.x;
    int orig = (t < M) ? blockSums[t] : 0;
    s[t] = orig;
    __syncthreads();
    for (int off = 1; off < 1024; off <<= 1) {
        int v = (t >= off) ? s[t - off] : 0;
        __syncthreads();
        s[t] += v;
        __syncthreads();
    }
    if (t < M) blockSums[t] = s[t] - orig;   // exclusive
}

// Scan step 3: block-local exclusive scan + block prefix -> offsets[]
__global__ __launch_bounds__(256) void scan_final(
    const int* __restrict__ count, const int* __restrict__ blockSums,
    int* __restrict__ offsets, int N)
{
    __shared__ int s[256];
    int t = threadIdx.x;
    int i = blockIdx.x * 256 + t;
    int orig = (i < N) ? count[i] : 0;
    s[t] = orig;
    __syncthreads();
    for (int off = 1; off < 256; off <<= 1) {
        int v = (t >= off) ? s[t - off] : 0;
        __syncthreads();
        s[t] += v;
        __syncthreads();
    }
    if (i < N) offsets[i] = s[t] - orig + blockSums[blockIdx.x];
}

// Kernel 2: scatter cutoff-weighted compact features as fp16 (16 halfs = one
// aligned 32B segment per edge) to CSR position. Reads streamed, writes packed.
__global__ __launch_bounds__(256) void scatter_payload(
    const float* __restrict__ edge_sca,
    const float* __restrict__ edge_vec,
    const float* __restrict__ gds,
    const int* __restrict__ eidx,
    const int* __restrict__ slotOf,
    const int* __restrict__ offsets,
    __half* __restrict__ payload,
    int E)
{
    int e = blockIdx.x * blockDim.x + threadIdx.x;
    if (e >= E) return;

    int src = eidx[e];
    float d = gds[e];
    float c = 0.0f;
    if (d >= 0.0f && d <= CUTOFF_F)
        c = 0.5f * (__cosf(d * PI_OVER_CUTOFF) + 1.0f);

    const float* es = edge_sca + (size_t)e * 6;
    const float* ev = edge_vec + (size_t)e * 9;

    union { __half h[16]; uint4 u[2]; } pk;
#pragma unroll
    for (int i = 0; i < 6; ++i) pk.h[i] = __float2half(c * es[i]);
    pk.h[6] = __float2half(c);
#pragma unroll
    for (int i = 0; i < 9; ++i) pk.h[7 + i] = __float2half(c * ev[i]);

    uint4* pb = (uint4*)(payload + (size_t)(offsets[src] + slotOf[e]) * 16);
    pb[0] = pk.u[0];
    pb[1] = pk.u[1];
}

// ===========================================================================
// Fallback kernels (bucket path / atomic path)
// ===========================================================================
__global__ __launch_bounds__(256) void fill_buckets(
    const int* __restrict__ eidx, int* __restrict__ count,
    int* __restrict__ bucket, int E)
{
    int e = blockIdx.x * blockDim.x + threadIdx.x;
    if (e >= E) return;
    int src = eidx[e];
    int slot = atomicAdd(&count[src], 1);
    if (slot < KCAP) bucket[src * KCAP + slot] = e;
}

__global__ __launch_bounds__(256) void edge_aggregate(
    const float* __restrict__ edge_sca, const float* __restrict__ edge_vec,
    const float* __restrict__ gds, const int* __restrict__ eidx,
    float* __restrict__ aggr, int E)
{
    int e = blockIdx.x * blockDim.x + threadIdx.x;
    if (e >= E) return;
    int src = eidx[e];
    float d = gds[e];
    float coeff = 0.0f;
    if (d >= 0.0f && d <= CUTOFF_F)
        coeff = 0.5f * (__cosf(d * PI_OVER_CUTOFF) + 1.0f);
    float* base = aggr + (size_t)src * 16;
    const float* es = edge_sca + (size_t)e * 6;
    const float* ev = edge_vec + (size_t)e * 9;
#pragma unroll
    for (int c = 0; c < 6; ++c) atomicAdd(base + c, coeff * es[c]);
    atomicAdd(base + 6, coeff);
#pragma unroll
    for (int k = 0; k < 9; ++k) atomicAdd(base + 7 + k, coeff * ev[k]);
}

// ===========================================================================
// Fused node kernel. mode: 2 = CSR fp16 payload, 1 = bucket gather, 0 = aggr.
// 16 lanes per node, 16 nodes per 256-block.
// ===========================================================================
__global__ __launch_bounds__(256) void node_fused(
    const float* __restrict__ node_sca,
    const float* __restrict__ node_vec,
    const float* __restrict__ edge_sca,
    const float* __restrict__ edge_vec,
    const float* __restrict__ gds,
    const int* __restrict__ count,
    const int* __restrict__ bucket,      // mode 1
    const int* __restrict__ offsets,     // mode 2
    const __half* __restrict__ payload,  // mode 2
    const float* __restrict__ aggr,      // mode 0
    const float* __restrict__ W_nss, const float* __restrict__ b_nss,
    const float* __restrict__ W_ess, const float* __restrict__ b_ess,
    const float* __restrict__ W_nsv, const float* __restrict__ b_nsv,
    const float* __restrict__ W_esv, const float* __restrict__ b_esv,
    const float* __restrict__ W_nvv, const float* __restrict__ W_evv,
    const float* __restrict__ W_lv,  const float* __restrict__ W_lv2,
    const float* __restrict__ W_ls,
    const float* __restrict__ W_gate, const float* __restrict__ b_gate,
    const float* __restrict__ W_dir,
    float* __restrict__ out,
    int N, int mode)
{
    // ---- weights in LDS ----
    __shared__ float sW_nss[64],  sb_nss[16];
    __shared__ float sW_ess[96],  sb_ess[16];
    __shared__ float sW_nsv[64],  sb_nsv[16];
    __shared__ float sW_esv[96],  sb_esv[16];
    __shared__ float sW_nvv[48],  sW_evv[48];
    __shared__ float sW_lv[256],  sW_lv2[256];
    __shared__ float sW_ls[512];
    __shared__ float sW_gate[256], sb_gate[16];
    __shared__ float sW_dir[256];

    // ---- per-node scratch (odd node-strides -> no bank conflicts) ----
    __shared__ float s_in  [16 * 33];
    __shared__ float s_avec[16 * 49];
    __shared__ float s_cat [16 * 33];
    __shared__ float s_vint[16 * 49];
    __shared__ float s_osca[16 * 17];
    __shared__ float s_ovec[16 * 49];

    const int t = threadIdx.x;
    {
        for (int i = t; i < 64;  i += 256) { sW_nss[i] = W_nss[i]; sW_nsv[i] = W_nsv[i]; }
        for (int i = t; i < 96;  i += 256) { sW_ess[i] = W_ess[i]; sW_esv[i] = W_esv[i]; }
        for (int i = t; i < 48;  i += 256) { sW_nvv[i] = W_nvv[i]; sW_evv[i] = W_evv[i]; }
        for (int i = t; i < 256; i += 256) {
            sW_lv[i]   = W_lv[i];
            sW_lv2[i]  = W_lv2[i];
            sW_gate[i] = W_gate[i];
            sW_dir[i]  = W_dir[i];
        }
        for (int i = t; i < 512; i += 256) sW_ls[i] = W_ls[i];
        if (t < 16) {
            sb_nss[t]  = b_nss[t];
            sb_ess[t]  = b_ess[t];
            sb_nsv[t]  = b_nsv[t];
            sb_esv[t]  = b_esv[t];
            sb_gate[t] = b_gate[t];
        }
    }

    const int slot = t >> 4;
    const int o    = t & 15;
    const int n    = blockIdx.x * 16 + slot;
    const bool valid = (n < N);

    if (valid) {
        if (o < 4) s_in[slot * 33 + o]     = node_sca[(size_t)n * 4 + o];
        if (o < 9) s_in[slot * 33 + 4 + o] = node_vec[(size_t)n * 9 + o];
    }

    if (mode == 2) {
        // CSR gather: each node's 16 lanes read contiguous 32B segments.
        float a0 = 0.f, a1 = 0.f, a2 = 0.f, a3 = 0.f;
        if (valid) {
            int cnt = count[n];
            const __half* p = payload + (size_t)offsets[n] * 16 + o;
            int s = 0;
            for (; s + 3 < cnt; s += 4) {
                a0 += __half2float(p[(size_t)(s + 0) * 16]);
                a1 += __half2float(p[(size_t)(s + 1) * 16]);
                a2 += __half2float(p[(size_t)(s + 2) * 16]);
                a3 += __half2float(p[(size_t)(s + 3) * 16]);
            }
            for (; s < cnt; ++s)
                a0 += __half2float(p[(size_t)s * 16]);
            s_in[slot * 33 + 13 + o] = (a0 + a1) + (a2 + a3);
        }
    } else if (mode == 1) {
        float acc = 0.0f;
        int cnt = valid ? count[n] : 0;
        if (cnt > KCAP) cnt = KCAP;
        const int* bk = bucket + (size_t)n * KCAP;
        for (int s = 0; s < cnt; ++s) {
            int e = bk[s];
            float d = gds[e];
            float coeff = 0.0f;
            if (d >= 0.0f && d <= CUTOFF_F)
                coeff = 0.5f * (__cosf(d * PI_OVER_CUTOFF) + 1.0f);
            float feat;
            if (o < 6)       feat = edge_sca[(size_t)e * 6 + o];
            else if (o == 6) feat = 1.0f;
            else             feat = edge_vec[(size_t)e * 9 + (o - 7)];
            acc += coeff * feat;
        }
        if (valid) s_in[slot * 33 + 13 + o] = acc;
    } else {
        if (valid) s_in[slot * 33 + 13 + o] = aggr[(size_t)n * 16 + o];
    }
    __syncthreads();

    const float* in = s_in + slot * 33;

    float nss = sb_nss[o], nsv = sb_nsv[o];
#pragma unroll
    for (int c = 0; c < 4; ++c) {
        float x = in[c];
        nss += x * sW_nss[c * 16 + o];
        nsv += x * sW_nsv[c * 16 + o];
    }
    float nvv0 = 0.f, nvv1 = 0.f, nvv2 = 0.f;
#pragma unroll
    for (int c = 0; c < 3; ++c) {
        float w = sW_nvv[c * 16 + o];
        nvv0 += in[4 + c * 3 + 0] * w;
        nvv1 += in[4 + c * 3 + 1] * w;
        nvv2 += in[4 + c * 3 + 2] * w;
    }
    float cc = in[19];
    float es = cc * sb_ess[o], ev = cc * sb_esv[o];
#pragma unroll
    for (int c = 0; c < 6; ++c) {
        float a = in[13 + c];
        es += a * sW_ess[c * 16 + o];
        ev += a * sW_esv[c * 16 + o];
    }
    float EV0 = 0.f, EV1 = 0.f, EV2 = 0.f;
#pragma unroll
    for (int c = 0; c < 3; ++c) {
        float w = sW_evv[c * 16 + o];
        EV0 += in[20 + c * 3 + 0] * w;
        EV1 += in[20 + c * 3 + 1] * w;
        EV2 += in[20 + c * 3 + 2] * w;
    }

    float asca = nss * es;
    float av0 = nvv0 * ev + nsv * EV0;
    float av1 = nvv1 * ev + nsv * EV1;
    float av2 = nvv2 * ev + nsv * EV2;
    s_avec[slot * 49 + o * 3 + 0] = av0;
    s_avec[slot * 49 + o * 3 + 1] = av1;
    s_avec[slot * 49 + o * 3 + 2] = av2;
    s_cat[slot * 33 + 16 + o] = asca;
    __syncthreads();

    float vi0 = 0.f, vi1 = 0.f, vi2 = 0.f;
#pragma unroll
    for (int c = 0; c < 16; ++c) {
        float w = sW_lv[c * 16 + o];
        const float* a = &s_avec[slot * 49 + c * 3];
        vi0 += a[0] * w; vi1 += a[1] * w; vi2 += a[2] * w;
    }
    float vnorm = sqrtf(vi0 * vi0 + vi1 * vi1 + vi2 * vi2);
    s_vint[slot * 49 + o * 3 + 0] = vi0;
    s_vint[slot * 49 + o * 3 + 1] = vi1;
    s_vint[slot * 49 + o * 3 + 2] = vi2;
    s_cat[slot * 33 + o] = vnorm;
    __syncthreads();

    float osca = 0.f;
#pragma unroll
    for (int c = 0; c < 32; ++c)
        osca += s_cat[slot * 33 + c] * sW_ls[c * 16 + o];
    float ov0 = 0.f, ov1 = 0.f, ov2 = 0.f;
#pragma unroll
    for (int c = 0; c < 16; ++c) {
        float w = sW_lv2[c * 16 + o];
        const float* a = &s_vint[slot * 49 + c * 3];
        ov0 += a[0] * w; ov1 += a[1] * w; ov2 += a[2] * w;
    }
    s_osca[slot * 17 + o] = osca;
    __syncthreads();

    float g = sb_gate[o];
#pragma unroll
    for (int c = 0; c < 16; ++c)
        g += s_osca[slot * 17 + c] * sW_gate[c * 16 + o];
    g = 1.0f / (1.0f + __expf(-g));
    ov0 *= g; ov1 *= g; ov2 *= g;
    s_ovec[slot * 49 + o * 3 + 0] = ov0;
    s_ovec[slot * 49 + o * 3 + 1] = ov1;
    s_ovec[slot * 49 + o * 3 + 2] = ov2;
    __syncthreads();

    float dv0 = 0.f, dv1 = 0.f, dv2 = 0.f;
#pragma unroll
    for (int c = 0; c < 16; ++c) {
        float w = sW_dir[c * 16 + o];
        const float* a = &s_ovec[slot * 49 + c * 3];
        dv0 += a[0] * w; dv1 += a[1] * w; dv2 += a[2] * w;
    }
    float dot = ov0 * dv0 + ov1 * dv1 + ov2 * dv2;
    if (dot < 0.0f) {
        float dn = dv0 * dv0 + dv1 * dv1 + dv2 * dv2;
        float f = 0.8f * dot / (dn + 1e-6f);
        ov0 -= f * dv0; ov1 -= f * dv1; ov2 -= f * dv2;
    }

    if (valid) {
        float so = (osca >= 0.0f) ? osca : 0.01f * osca;
        out[(size_t)n * 16 + o] = so;
        size_t vb = (size_t)N * 16 + (size_t)n * 48 + (size_t)o * 3;
        out[vb + 0] = ov0;
        out[vb + 1] = ov1;
        out[vb + 2] = ov2;
    }
}

extern "C" void kernel_launch(void* const* d_in, const int* in_sizes, int n_in,
                              void* d_out, int out_size, void* d_ws, size_t ws_size,
                              hipStream_t stream)
{
    const float* node_sca = (const float*)d_in[0];
    const float* node_vec = (const float*)d_in[1];
    const float* edge_sca = (const float*)d_in[2];
    const float* edge_vec = (const float*)d_in[3];
    const float* gds      = (const float*)d_in[4];
    const int*   eidx     = (const int*)d_in[5];

    const int N = in_sizes[0] / 4;   // node_sca is [N,4]
    const int E = in_sizes[4];       // gds_dist is [E]

    // ---- workspace layout for CSR path ----
    int*    count     = (int*)d_ws;                 // N
    int*    offsets   = count + N;                  // N
    int*    blockSums = offsets + N;                // 1024
    int*    slotOf    = blockSums + 1024;           // E
    size_t  hdr_bytes = ((size_t)(2 * N + 1024 + E) * 4 + 63) & ~(size_t)63;
    __half* payload   = (__half*)((char*)d_ws + hdr_bytes);
    size_t  need_csr  = hdr_bytes + (size_t)E * 16 * sizeof(__half);
    size_t  need_bkt  = (size_t)N * (1 + KCAP) * sizeof(int);

    const int nBlocksN = (N + 255) / 256;   // <= 1024 assumed (N <= 262144)

    int mode;
    if (ws_size >= need_csr && nBlocksN <= 1024) mode = 2;
    else if (ws_size >= need_bkt)                mode = 1;
    else                                         mode = 0;

    int* bucket = count + N;        // mode 1: N*KCAP ints after count
    float* aggr = (float*)d_ws;     // mode 0: N*16 floats

    if (mode == 2) {
        hipMemsetAsync(count, 0, (size_t)N * sizeof(int), stream);
        count_edges<<<(E + 255) / 256, 256, 0, stream>>>(eidx, count, slotOf, E);
        scan_block_sums<<<nBlocksN, 256, 0, stream>>>(count, blockSums, N);
        scan_exclusive_small<<<1, 1024, 0, stream>>>(blockSums, nBlocksN);
        scan_final<<<nBlocksN, 256, 0, stream>>>(count, blockSums, offsets, N);
        scatter_payload<<<(E + 255) / 256, 256, 0, stream>>>(
            edge_sca, edge_vec, gds, eidx, slotOf, offsets, payload, E);
    } else if (mode == 1) {
        hipMemsetAsync(count, 0, (size_t)N * sizeof(int), stream);
        fill_buckets<<<(E + 255) / 256, 256, 0, stream>>>(eidx, count, bucket, E);
    } else {
        hipMemsetAsync(aggr, 0, (size_t)N * 16 * sizeof(float), stream);
        edge_aggregate<<<(E + 255) / 256, 256, 0, stream>>>(
            edge_sca, edge_vec, gds, eidx, aggr, E);
    }

    node_fused<<<(N + 15) / 16, 256, 0, stream>>>(
        node_sca, node_vec, edge_sca, edge_vec, gds,
        count, bucket, offsets, payload, aggr,
        (const float*)d_in[6],  (const float*)d_in[7],
        (const float*)d_in[8],  (const float*)d_in[9],
        (const float*)d_in[10], (const float*)d_in[11],
        (const float*)d_in[12], (const float*)d_in[13],
        (const float*)d_in[14], (const float*)d_in[15],
        (const float*)d_in[16], (const float*)d_in[17],
        (const float*)d_in[18],
        (const float*)d_in[19], (const float*)d_in[20],
        (const float*)d_in[21],
        (float*)d_out, N, mode);
}

// Round 6
// 305.655 us; speedup vs baseline: 4.8873x; 1.1714x over previous
//
#include <hip/hip_runtime.h>
#include <hip/hip_fp16.h>
#include <math.h>

// Problem constants (match reference)
#define CUTOFF_F 10.0f
#define PI_OVER_CUTOFF 0.31415926535897931f  // pi/10
#define KCAP 64    // mode-1 fallback bucket capacity (edge ids)
#define KCAP3 32   // mode-3 payload bucket capacity; overflow -> fp32 atomics

// ===========================================================================
// Mode 3 (primary): fused ticket + payload scatter. One pass over edges:
// stream features, 1 int atomic ticket, one 32B packed fp16 write. Overflow
// (slot >= KCAP3, ~tens of edges at Poisson(16)) goes to fp32 atomics in aggr.
// ===========================================================================
__global__ __launch_bounds__(256) void bucket_scatter(
    const float* __restrict__ edge_sca,
    const float* __restrict__ edge_vec,
    const float* __restrict__ gds,
    const int* __restrict__ eidx,
    int* __restrict__ count,
    __half* __restrict__ bucket,   // [N*KCAP3*16] halfs
    float* __restrict__ aggr,      // [N*16] overflow accumulator (zeroed)
    int E)
{
    int e = blockIdx.x * blockDim.x + threadIdx.x;
    if (e >= E) return;

    int src = eidx[e];
    float d = gds[e];
    float c = 0.0f;
    if (d >= 0.0f && d <= CUTOFF_F)
        c = 0.5f * (__cosf(d * PI_OVER_CUTOFF) + 1.0f);

    const float* es = edge_sca + (size_t)e * 6;
    const float* ev = edge_vec + (size_t)e * 9;

    float f[16];
#pragma unroll
    for (int i = 0; i < 6; ++i) f[i] = c * es[i];
    f[6] = c;
#pragma unroll
    for (int i = 0; i < 9; ++i) f[7 + i] = c * ev[i];

    int slot = atomicAdd(&count[src], 1);
    if (slot < KCAP3) {
        union { __half h[16]; uint4 u[2]; } pk;
#pragma unroll
        for (int i = 0; i < 16; ++i) pk.h[i] = __float2half(f[i]);
        uint4* pb = (uint4*)(bucket + ((size_t)src * KCAP3 + slot) * 16);
        pb[0] = pk.u[0];
        pb[1] = pk.u[1];
    } else {
        float* base = aggr + (size_t)src * 16;
#pragma unroll
        for (int i = 0; i < 16; ++i) atomicAdd(base + i, f[i]);
    }
}

// ===========================================================================
// CSR path (mode 2 fallback)
// ===========================================================================
__global__ __launch_bounds__(256) void count_edges(
    const int* __restrict__ eidx, int* __restrict__ count,
    int* __restrict__ slotOf, int E)
{
    int e = blockIdx.x * blockDim.x + threadIdx.x;
    if (e >= E) return;
    int src = eidx[e];
    slotOf[e] = atomicAdd(&count[src], 1);
}

__global__ __launch_bounds__(256) void scan_block_sums(
    const int* __restrict__ count, int* __restrict__ blockSums, int N)
{
    __shared__ int sdata[256];
    int t = threadIdx.x;
    int i = blockIdx.x * 256 + t;
    sdata[t] = (i < N) ? count[i] : 0;
    __syncthreads();
    for (int off = 128; off > 0; off >>= 1) {
        if (t < off) sdata[t] += sdata[t + off];
        __syncthreads();
    }
    if (t == 0) blockSums[blockIdx.x] = sdata[0];
}

__global__ __launch_bounds__(1024) void scan_exclusive_small(
    int* __restrict__ blockSums, int M)
{
    __shared__ int s[1024];
    int t = threadIdx.x;
    int orig = (t < M) ? blockSums[t] : 0;
    s[t] = orig;
    __syncthreads();
    for (int off = 1; off < 1024; off <<= 1) {
        int v = (t >= off) ? s[t - off] : 0;
        __syncthreads();
        s[t] += v;
        __syncthreads();
    }
    if (t < M) blockSums[t] = s[t] - orig;
}

__global__ __launch_bounds__(256) void scan_final(
    const int* __restrict__ count, const int* __restrict__ blockSums,
    int* __restrict__ offsets, int N)
{
    __shared__ int s[256];
    int t = threadIdx.x;
    int i = blockIdx.x * 256 + t;
    int orig = (i < N) ? count[i] : 0;
    s[t] = orig;
    __syncthreads();
    for (int off = 1; off < 256; off <<= 1) {
        int v = (t >= off) ? s[t - off] : 0;
        __syncthreads();
        s[t] += v;
        __syncthreads();
    }
    if (i < N) offsets[i] = s[t] - orig + blockSums[blockIdx.x];
}

__global__ __launch_bounds__(256) void scatter_payload(
    const float* __restrict__ edge_sca, const float* __restrict__ edge_vec,
    const float* __restrict__ gds, const int* __restrict__ eidx,
    const int* __restrict__ slotOf, const int* __restrict__ offsets,
    __half* __restrict__ payload, int E)
{
    int e = blockIdx.x * blockDim.x + threadIdx.x;
    if (e >= E) return;
    int src = eidx[e];
    float d = gds[e];
    float c = 0.0f;
    if (d >= 0.0f && d <= CUTOFF_F)
        c = 0.5f * (__cosf(d * PI_OVER_CUTOFF) + 1.0f);
    const float* es = edge_sca + (size_t)e * 6;
    const float* ev = edge_vec + (size_t)e * 9;
    union { __half h[16]; uint4 u[2]; } pk;
#pragma unroll
    for (int i = 0; i < 6; ++i) pk.h[i] = __float2half(c * es[i]);
    pk.h[6] = __float2half(c);
#pragma unroll
    for (int i = 0; i < 9; ++i) pk.h[7 + i] = __float2half(c * ev[i]);
    uint4* pb = (uint4*)(payload + (size_t)(offsets[src] + slotOf[e]) * 16);
    pb[0] = pk.u[0];
    pb[1] = pk.u[1];
}

// ===========================================================================
// Modes 1 / 0 fallbacks
// ===========================================================================
__global__ __launch_bounds__(256) void fill_buckets(
    const int* __restrict__ eidx, int* __restrict__ count,
    int* __restrict__ bucket, int E)
{
    int e = blockIdx.x * blockDim.x + threadIdx.x;
    if (e >= E) return;
    int src = eidx[e];
    int slot = atomicAdd(&count[src], 1);
    if (slot < KCAP) bucket[src * KCAP + slot] = e;
}

__global__ __launch_bounds__(256) void edge_aggregate(
    const float* __restrict__ edge_sca, const float* __restrict__ edge_vec,
    const float* __restrict__ gds, const int* __restrict__ eidx,
    float* __restrict__ aggr, int E)
{
    int e = blockIdx.x * blockDim.x + threadIdx.x;
    if (e >= E) return;
    int src = eidx[e];
    float d = gds[e];
    float coeff = 0.0f;
    if (d >= 0.0f && d <= CUTOFF_F)
        coeff = 0.5f * (__cosf(d * PI_OVER_CUTOFF) + 1.0f);
    float* base = aggr + (size_t)src * 16;
    const float* es = edge_sca + (size_t)e * 6;
    const float* ev = edge_vec + (size_t)e * 9;
#pragma unroll
    for (int c = 0; c < 6; ++c) atomicAdd(base + c, coeff * es[c]);
    atomicAdd(base + 6, coeff);
#pragma unroll
    for (int k = 0; k < 9; ++k) atomicAdd(base + 7 + k, coeff * ev[k]);
}

// ===========================================================================
// Fused node kernel. mode: 3 = fixed-stride fp16 bucket (+aggr overflow),
// 2 = CSR fp16 payload, 1 = bucket ids, 0 = aggr only.
// 16 lanes per node, 16 nodes per 256-block.
// ===========================================================================
__global__ __launch_bounds__(256) void node_fused(
    const float* __restrict__ node_sca,
    const float* __restrict__ node_vec,
    const float* __restrict__ edge_sca,
    const float* __restrict__ edge_vec,
    const float* __restrict__ gds,
    const int* __restrict__ count,
    const int* __restrict__ bucket,      // mode 1
    const int* __restrict__ offsets,     // mode 2
    const __half* __restrict__ payload,  // mode 2 (CSR) / mode 3 (fixed-stride)
    const float* __restrict__ aggr,      // mode 0 / mode 3 overflow
    const float* __restrict__ W_nss, const float* __restrict__ b_nss,
    const float* __restrict__ W_ess, const float* __restrict__ b_ess,
    const float* __restrict__ W_nsv, const float* __restrict__ b_nsv,
    const float* __restrict__ W_esv, const float* __restrict__ b_esv,
    const float* __restrict__ W_nvv, const float* __restrict__ W_evv,
    const float* __restrict__ W_lv,  const float* __restrict__ W_lv2,
    const float* __restrict__ W_ls,
    const float* __restrict__ W_gate, const float* __restrict__ b_gate,
    const float* __restrict__ W_dir,
    float* __restrict__ out,
    int N, int mode)
{
    // ---- weights in LDS ----
    __shared__ float sW_nss[64],  sb_nss[16];
    __shared__ float sW_ess[96],  sb_ess[16];
    __shared__ float sW_nsv[64],  sb_nsv[16];
    __shared__ float sW_esv[96],  sb_esv[16];
    __shared__ float sW_nvv[48],  sW_evv[48];
    __shared__ float sW_lv[256],  sW_lv2[256];
    __shared__ float sW_ls[512];
    __shared__ float sW_gate[256], sb_gate[16];
    __shared__ float sW_dir[256];

    // ---- per-node scratch (odd node-strides -> no bank conflicts) ----
    __shared__ float s_in  [16 * 33];
    __shared__ float s_avec[16 * 49];
    __shared__ float s_cat [16 * 33];
    __shared__ float s_vint[16 * 49];
    __shared__ float s_osca[16 * 17];
    __shared__ float s_ovec[16 * 49];

    const int t = threadIdx.x;
    {
        for (int i = t; i < 64;  i += 256) { sW_nss[i] = W_nss[i]; sW_nsv[i] = W_nsv[i]; }
        for (int i = t; i < 96;  i += 256) { sW_ess[i] = W_ess[i]; sW_esv[i] = W_esv[i]; }
        for (int i = t; i < 48;  i += 256) { sW_nvv[i] = W_nvv[i]; sW_evv[i] = W_evv[i]; }
        for (int i = t; i < 256; i += 256) {
            sW_lv[i]   = W_lv[i];
            sW_lv2[i]  = W_lv2[i];
            sW_gate[i] = W_gate[i];
            sW_dir[i]  = W_dir[i];
        }
        for (int i = t; i < 512; i += 256) sW_ls[i] = W_ls[i];
        if (t < 16) {
            sb_nss[t]  = b_nss[t];
            sb_ess[t]  = b_ess[t];
            sb_nsv[t]  = b_nsv[t];
            sb_esv[t]  = b_esv[t];
            sb_gate[t] = b_gate[t];
        }
    }

    const int slot = t >> 4;
    const int o    = t & 15;
    const int n    = blockIdx.x * 16 + slot;
    const bool valid = (n < N);

    if (valid) {
        if (o < 4) s_in[slot * 33 + o]     = node_sca[(size_t)n * 4 + o];
        if (o < 9) s_in[slot * 33 + 4 + o] = node_vec[(size_t)n * 9 + o];
    }

    if (mode == 3) {
        float a0 = 0.f, a1 = 0.f, a2 = 0.f, a3 = 0.f;
        if (valid) {
            int cnt = count[n];
            if (cnt > KCAP3) cnt = KCAP3;
            const __half* p = payload + (size_t)n * KCAP3 * 16 + o;
            int s = 0;
            for (; s + 3 < cnt; s += 4) {
                a0 += __half2float(p[(s + 0) * 16]);
                a1 += __half2float(p[(s + 1) * 16]);
                a2 += __half2float(p[(s + 2) * 16]);
                a3 += __half2float(p[(s + 3) * 16]);
            }
            for (; s < cnt; ++s)
                a0 += __half2float(p[s * 16]);
            // overflow contributions (fp32 atomics target, zero if none)
            a1 += aggr[(size_t)n * 16 + o];
            s_in[slot * 33 + 13 + o] = (a0 + a1) + (a2 + a3);
        }
    } else if (mode == 2) {
        float a0 = 0.f, a1 = 0.f, a2 = 0.f, a3 = 0.f;
        if (valid) {
            int cnt = count[n];
            const __half* p = payload + (size_t)offsets[n] * 16 + o;
            int s = 0;
            for (; s + 3 < cnt; s += 4) {
                a0 += __half2float(p[(size_t)(s + 0) * 16]);
                a1 += __half2float(p[(size_t)(s + 1) * 16]);
                a2 += __half2float(p[(size_t)(s + 2) * 16]);
                a3 += __half2float(p[(size_t)(s + 3) * 16]);
            }
            for (; s < cnt; ++s)
                a0 += __half2float(p[(size_t)s * 16]);
            s_in[slot * 33 + 13 + o] = (a0 + a1) + (a2 + a3);
        }
    } else if (mode == 1) {
        float acc = 0.0f;
        int cnt = valid ? count[n] : 0;
        if (cnt > KCAP) cnt = KCAP;
        const int* bk = bucket + (size_t)n * KCAP;
        for (int s = 0; s < cnt; ++s) {
            int e = bk[s];
            float d = gds[e];
            float coeff = 0.0f;
            if (d >= 0.0f && d <= CUTOFF_F)
                coeff = 0.5f * (__cosf(d * PI_OVER_CUTOFF) + 1.0f);
            float feat;
            if (o < 6)       feat = edge_sca[(size_t)e * 6 + o];
            else if (o == 6) feat = 1.0f;
            else             feat = edge_vec[(size_t)e * 9 + (o - 7)];
            acc += coeff * feat;
        }
        if (valid) s_in[slot * 33 + 13 + o] = acc;
    } else {
        if (valid) s_in[slot * 33 + 13 + o] = aggr[(size_t)n * 16 + o];
    }
    __syncthreads();

    const float* in = s_in + slot * 33;

    float nss = sb_nss[o], nsv = sb_nsv[o];
#pragma unroll
    for (int c = 0; c < 4; ++c) {
        float x = in[c];
        nss += x * sW_nss[c * 16 + o];
        nsv += x * sW_nsv[c * 16 + o];
    }
    float nvv0 = 0.f, nvv1 = 0.f, nvv2 = 0.f;
#pragma unroll
    for (int c = 0; c < 3; ++c) {
        float w = sW_nvv[c * 16 + o];
        nvv0 += in[4 + c * 3 + 0] * w;
        nvv1 += in[4 + c * 3 + 1] * w;
        nvv2 += in[4 + c * 3 + 2] * w;
    }
    float cc = in[19];
    float es = cc * sb_ess[o], ev = cc * sb_esv[o];
#pragma unroll
    for (int c = 0; c < 6; ++c) {
        float a = in[13 + c];
        es += a * sW_ess[c * 16 + o];
        ev += a * sW_esv[c * 16 + o];
    }
    float EV0 = 0.f, EV1 = 0.f, EV2 = 0.f;
#pragma unroll
    for (int c = 0; c < 3; ++c) {
        float w = sW_evv[c * 16 + o];
        EV0 += in[20 + c * 3 + 0] * w;
        EV1 += in[20 + c * 3 + 1] * w;
        EV2 += in[20 + c * 3 + 2] * w;
    }

    float asca = nss * es;
    float av0 = nvv0 * ev + nsv * EV0;
    float av1 = nvv1 * ev + nsv * EV1;
    float av2 = nvv2 * ev + nsv * EV2;
    s_avec[slot * 49 + o * 3 + 0] = av0;
    s_avec[slot * 49 + o * 3 + 1] = av1;
    s_avec[slot * 49 + o * 3 + 2] = av2;
    s_cat[slot * 33 + 16 + o] = asca;
    __syncthreads();

    float vi0 = 0.f, vi1 = 0.f, vi2 = 0.f;
#pragma unroll
    for (int c = 0; c < 16; ++c) {
        float w = sW_lv[c * 16 + o];
        const float* a = &s_avec[slot * 49 + c * 3];
        vi0 += a[0] * w; vi1 += a[1] * w; vi2 += a[2] * w;
    }
    float vnorm = sqrtf(vi0 * vi0 + vi1 * vi1 + vi2 * vi2);
    s_vint[slot * 49 + o * 3 + 0] = vi0;
    s_vint[slot * 49 + o * 3 + 1] = vi1;
    s_vint[slot * 49 + o * 3 + 2] = vi2;
    s_cat[slot * 33 + o] = vnorm;
    __syncthreads();

    float osca = 0.f;
#pragma unroll
    for (int c = 0; c < 32; ++c)
        osca += s_cat[slot * 33 + c] * sW_ls[c * 16 + o];
    float ov0 = 0.f, ov1 = 0.f, ov2 = 0.f;
#pragma unroll
    for (int c = 0; c < 16; ++c) {
        float w = sW_lv2[c * 16 + o];
        const float* a = &s_vint[slot * 49 + c * 3];
        ov0 += a[0] * w; ov1 += a[1] * w; ov2 += a[2] * w;
    }
    s_osca[slot * 17 + o] = osca;
    __syncthreads();

    float g = sb_gate[o];
#pragma unroll
    for (int c = 0; c < 16; ++c)
        g += s_osca[slot * 17 + c] * sW_gate[c * 16 + o];
    g = 1.0f / (1.0f + __expf(-g));
    ov0 *= g; ov1 *= g; ov2 *= g;
    s_ovec[slot * 49 + o * 3 + 0] = ov0;
    s_ovec[slot * 49 + o * 3 + 1] = ov1;
    s_ovec[slot * 49 + o * 3 + 2] = ov2;
    __syncthreads();

    float dv0 = 0.f, dv1 = 0.f, dv2 = 0.f;
#pragma unroll
    for (int c = 0; c < 16; ++c) {
        float w = sW_dir[c * 16 + o];
        const float* a = &s_ovec[slot * 49 + c * 3];
        dv0 += a[0] * w; dv1 += a[1] * w; dv2 += a[2] * w;
    }
    float dot = ov0 * dv0 + ov1 * dv1 + ov2 * dv2;
    if (dot < 0.0f) {
        float dn = dv0 * dv0 + dv1 * dv1 + dv2 * dv2;
        float f = 0.8f * dot / (dn + 1e-6f);
        ov0 -= f * dv0; ov1 -= f * dv1; ov2 -= f * dv2;
    }

    if (valid) {
        float so = (osca >= 0.0f) ? osca : 0.01f * osca;
        out[(size_t)n * 16 + o] = so;
        size_t vb = (size_t)N * 16 + (size_t)n * 48 + (size_t)o * 3;
        out[vb + 0] = ov0;
        out[vb + 1] = ov1;
        out[vb + 2] = ov2;
    }
}

extern "C" void kernel_launch(void* const* d_in, const int* in_sizes, int n_in,
                              void* d_out, int out_size, void* d_ws, size_t ws_size,
                              hipStream_t stream)
{
    const float* node_sca = (const float*)d_in[0];
    const float* node_vec = (const float*)d_in[1];
    const float* edge_sca = (const float*)d_in[2];
    const float* edge_vec = (const float*)d_in[3];
    const float* gds      = (const float*)d_in[4];
    const int*   eidx     = (const int*)d_in[5];

    const int N = in_sizes[0] / 4;   // node_sca is [N,4]
    const int E = in_sizes[4];       // gds_dist is [E]

    // ---- mode-3 layout: [count N][aggr N*16 floats][bucket N*KCAP3*16 halfs]
    int*    count3  = (int*)d_ws;
    float*  aggr3   = (float*)(count3 + N);
    __half* bucket3 = (__half*)(aggr3 + (size_t)N * 16);
    size_t  need3   = (size_t)N * 4 + (size_t)N * 64
                    + (size_t)N * KCAP3 * 16 * sizeof(__half);

    // ---- mode-2 (CSR) layout ----
    int*    count     = (int*)d_ws;
    int*    offsets   = count + N;
    int*    blockSums = offsets + N;
    int*    slotOf    = blockSums + 1024;
    size_t  hdr_bytes = ((size_t)(2 * N + 1024 + E) * 4 + 63) & ~(size_t)63;
    __half* payload   = (__half*)((char*)d_ws + hdr_bytes);
    size_t  need_csr  = hdr_bytes + (size_t)E * 16 * sizeof(__half);
    size_t  need_bkt  = (size_t)N * (1 + KCAP) * sizeof(int);

    const int nBlocksN = (N + 255) / 256;   // <= 1024 assumed

    int mode;
    if (ws_size >= need3)                          mode = 3;
    else if (ws_size >= need_csr && nBlocksN <= 1024) mode = 2;
    else if (ws_size >= need_bkt)                  mode = 1;
    else                                           mode = 0;

    int* bucket = count + N;        // mode 1
    float* aggr = (float*)d_ws;     // mode 0

    if (mode == 3) {
        // zero count + overflow aggr in one memset (they're adjacent)
        hipMemsetAsync(count3, 0, (size_t)N * 4 + (size_t)N * 64, stream);
        bucket_scatter<<<(E + 255) / 256, 256, 0, stream>>>(
            edge_sca, edge_vec, gds, eidx, count3, bucket3, aggr3, E);
        node_fused<<<(N + 15) / 16, 256, 0, stream>>>(
            node_sca, node_vec, edge_sca, edge_vec, gds,
            count3, bucket, offsets, bucket3, aggr3,
            (const float*)d_in[6],  (const float*)d_in[7],
            (const float*)d_in[8],  (const float*)d_in[9],
            (const float*)d_in[10], (const float*)d_in[11],
            (const float*)d_in[12], (const float*)d_in[13],
            (const float*)d_in[14], (const float*)d_in[15],
            (const float*)d_in[16], (const float*)d_in[17],
            (const float*)d_in[18],
            (const float*)d_in[19], (const float*)d_in[20],
            (const float*)d_in[21],
            (float*)d_out, N, 3);
        return;
    }

    if (mode == 2) {
        hipMemsetAsync(count, 0, (size_t)N * sizeof(int), stream);
        count_edges<<<(E + 255) / 256, 256, 0, stream>>>(eidx, count, slotOf, E);
        scan_block_sums<<<nBlocksN, 256, 0, stream>>>(count, blockSums, N);
        scan_exclusive_small<<<1, 1024, 0, stream>>>(blockSums, nBlocksN);
        scan_final<<<nBlocksN, 256, 0, stream>>>(count, blockSums, offsets, N);
        scatter_payload<<<(E + 255) / 256, 256, 0, stream>>>(
            edge_sca, edge_vec, gds, eidx, slotOf, offsets, payload, E);
    } else if (mode == 1) {
        hipMemsetAsync(count, 0, (size_t)N * sizeof(int), stream);
        fill_buckets<<<(E + 255) / 256, 256, 0, stream>>>(eidx, count, bucket, E);
    } else {
        hipMemsetAsync(aggr, 0, (size_t)N * 16 * sizeof(float), stream);
        edge_aggregate<<<(E + 255) / 256, 256, 0, stream>>>(
            edge_sca, edge_vec, gds, eidx, aggr, E);
    }

    node_fused<<<(N + 15) / 16, 256, 0, stream>>>(
        node_sca, node_vec, edge_sca, edge_vec, gds,
        count, bucket, offsets, payload, aggr,
        (const float*)d_in[6],  (const float*)d_in[7],
        (const float*)d_in[8],  (const float*)d_in[9],
        (const float*)d_in[10], (const float*)d_in[11],
        (const float*)d_in[12], (const float*)d_in[13],
        (const float*)d_in[14], (const float*)d_in[15],
        (const float*)d_in[16], (const float*)d_in[17],
        (const float*)d_in[18],
        (const float*)d_in[19], (const float*)d_in[20],
        (const float*)d_in[21],
        (float*)d_out, N, mode);
}